// Round 2
// baseline (191.868 us; speedup 1.0000x reference)
//
#include <hip/hip_runtime.h>
#include <hip/hip_bf16.h>

// RelMHAtt: B=4, N=512, H=16, D=64, HS=1024, RS=64, SCALE=0.125
// Pipeline: detect_mask -> wtrans -> proj_gemm(q,k,v) -> bias_kernel -> attn_kernel -> out_gemm

typedef __bf16 bf16_t;
typedef __bf16 bf16x8 __attribute__((ext_vector_type(8)));
typedef float f32x4 __attribute__((ext_vector_type(4)));

__device__ __forceinline__ f32x4 mfma16(bf16x8 a, bf16x8 b, f32x4 c) {
  return __builtin_amdgcn_mfma_f32_16x16x32_bf16(a, b, c, 0, 0, 0);
}
__device__ __forceinline__ f32x4 zero4() {
  f32x4 z; z[0] = 0.f; z[1] = 0.f; z[2] = 0.f; z[3] = 0.f; return z;
}

// ---------------------------------------------------------------------------
// Mask dtype probe: if mask is uint8/bool (1B/elem), the uint32 view of the
// first 16KB almost surely contains words > 1 (packed 0/1 bytes). If int32,
// every word is 0 or 1. flag=1 -> u8 path, flag=0 -> i32 path.
__global__ __launch_bounds__(256) void detect_mask(const unsigned int* __restrict__ mw,
                                                   int* __restrict__ flag) {
  __shared__ int s;
  if (threadIdx.x == 0) s = 0;
  __syncthreads();
  int any = 0;
  for (int i = threadIdx.x; i < 4096; i += 256) any |= (mw[i] > 1u) ? 1 : 0;
  if (any) atomicOr(&s, 1);
  __syncthreads();
  if (threadIdx.x == 0) *flag = s;
}

// ---------------------------------------------------------------------------
// Weight transpose + cast: W[1024][1024] f32 (in,out) -> Wt[1024][1024] bf16 (out,in)
__global__ __launch_bounds__(256) void wtrans_kernel(
    const float* __restrict__ W0, const float* __restrict__ W1,
    const float* __restrict__ W2, const float* __restrict__ W3,
    bf16_t* __restrict__ OutBase) {
  const float* W = blockIdx.z == 0 ? W0 : blockIdx.z == 1 ? W1 : blockIdx.z == 2 ? W2 : W3;
  bf16_t* Ot = OutBase + (size_t)blockIdx.z * 1024 * 1024;
  __shared__ float tile[64][68];
  const int tid = threadIdx.x;
  const int i0 = blockIdx.y * 64, j0 = blockIdx.x * 64;
  const int ri = tid >> 2, rc = (tid & 3) * 16;
  const float* src = W + (size_t)(i0 + ri) * 1024 + j0 + rc;
#pragma unroll
  for (int qq = 0; qq < 4; ++qq) {
    float4 f = *(const float4*)(src + qq * 4);
    *(float4*)(&tile[ri][rc + qq * 4]) = f;
  }
  __syncthreads();
  const int wj = tid >> 2, wc = (tid & 3) * 16;
  bf16x8 o0, o1;
#pragma unroll
  for (int s = 0; s < 8; ++s) o0[s] = (bf16_t)tile[wc + s][wj];
#pragma unroll
  for (int s = 0; s < 8; ++s) o1[s] = (bf16_t)tile[wc + 8 + s][wj];
  bf16_t* dst = Ot + (size_t)(j0 + wj) * 1024 + i0 + wc;
  *(bf16x8*)dst = o0;
  *(bf16x8*)(dst + 8) = o1;
}

// ---------------------------------------------------------------------------
// Projection GEMM: C = A(f32 [2048][1024]) x Bt(bf16 [1024][1024])^T,
// written bf16 into [b][h][n][d]. 128x128 tile, BK=64, 4 waves (2x2 of 64x64).
__global__ __launch_bounds__(256) void proj_gemm(
    const float* __restrict__ Aq, const float* __restrict__ Ak, const float* __restrict__ Av,
    const bf16_t* __restrict__ Bq, const bf16_t* __restrict__ Bk, const bf16_t* __restrict__ Bv,
    bf16_t* __restrict__ Oq, bf16_t* __restrict__ Ok, bf16_t* __restrict__ Ov) {
  const int z = blockIdx.z;
  const float* A = (z == 0) ? Aq : (z == 1) ? Ak : Av;
  const bf16_t* Bt = (z == 0) ? Bq : (z == 1) ? Bk : Bv;
  bf16_t* Out = (z == 0) ? Oq : (z == 1) ? Ok : Ov;
  __shared__ __align__(16) bf16_t Asm[128 * 64];
  __shared__ __align__(16) bf16_t Bsm[128 * 64];
  const int tid = threadIdx.x, wid = tid >> 6, lane = tid & 63;
  const int lg = lane >> 4, lc = lane & 15;
  const int m0 = blockIdx.y * 128, n0 = blockIdx.x * 128;
  const int wm = (wid >> 1) * 64, wn = (wid & 1) * 64;
  const int srow = tid >> 1, sc0 = (tid & 1) * 4;
  const float* Arow = A + (size_t)(m0 + srow) * 1024;
  const bf16_t* Brow = Bt + (size_t)(n0 + srow) * 1024;
  f32x4 acc[4][4];
#pragma unroll
  for (int i = 0; i < 4; ++i)
#pragma unroll
    for (int j = 0; j < 4; ++j) acc[i][j] = zero4();

  for (int k0 = 0; k0 < 1024; k0 += 64) {
#pragma unroll
    for (int ci = 0; ci < 4; ++ci) {
      const int c = sc0 + ci;
      const int phys = c ^ (srow & 7);
      const float4* s = (const float4*)(Arow + k0 + c * 8);
      float4 f0 = s[0], f1 = s[1];
      bf16x8 av;
      av[0] = (bf16_t)f0.x; av[1] = (bf16_t)f0.y; av[2] = (bf16_t)f0.z; av[3] = (bf16_t)f0.w;
      av[4] = (bf16_t)f1.x; av[5] = (bf16_t)f1.y; av[6] = (bf16_t)f1.z; av[7] = (bf16_t)f1.w;
      *(bf16x8*)(Asm + srow * 64 + phys * 8) = av;
      *(bf16x8*)(Bsm + srow * 64 + phys * 8) = *(const bf16x8*)(Brow + k0 + c * 8);
    }
    __syncthreads();
#pragma unroll
    for (int kk = 0; kk < 2; ++kk) {
      bf16x8 af[4], bfv[4];
#pragma unroll
      for (int i = 0; i < 4; ++i) {
        const int ar = wm + i * 16 + lc;
        af[i] = *(const bf16x8*)(Asm + ar * 64 + ((kk * 4 + lg) ^ (ar & 7)) * 8);
        const int brr = wn + i * 16 + lc;
        bfv[i] = *(const bf16x8*)(Bsm + brr * 64 + ((kk * 4 + lg) ^ (brr & 7)) * 8);
      }
#pragma unroll
      for (int mi = 0; mi < 4; ++mi)
#pragma unroll
        for (int ni = 0; ni < 4; ++ni) acc[mi][ni] = mfma16(af[mi], bfv[ni], acc[mi][ni]);
    }
    __syncthreads();
  }
#pragma unroll
  for (int mi = 0; mi < 4; ++mi)
#pragma unroll
    for (int ni = 0; ni < 4; ++ni)
#pragma unroll
      for (int j = 0; j < 4; ++j) {
        const int m = m0 + wm + mi * 16 + lg * 4 + j;
        const int col = n0 + wn + ni * 16 + lc;
        const int b = m >> 9, n = m & 511;
        const int h = col >> 6, d = col & 63;
        Out[(((size_t)(b * 16 + h)) * 512 + n) * 64 + d] = (bf16_t)acc[mi][ni][j];
      }
}

// ---------------------------------------------------------------------------
// Bias: r = relu(rel_embed @ Wr + br); bias = log(max(r,1e-6)); masked -> -1e9.
// Swapped-operand MFMA; output bf16 [B][H][N][N]. Mask dtype chosen via flag.
__global__ __launch_bounds__(256) void bias_kernel(
    const float* __restrict__ rel, const float* __restrict__ Wr,
    const float* __restrict__ br, const void* __restrict__ mask,
    const int* __restrict__ mflag, bf16_t* __restrict__ biasM) {
  const int tid = threadIdx.x, wid = tid >> 6, lane = tid & 63;
  const int lg = lane >> 4, lc = lane & 15;
  const int pair = blockIdx.x;  // b*512 + q
  const int b = pair >> 9, qrow = pair & 511;
  const int isU8 = *mflag;
  bf16x8 wf[2];
#pragma unroll
  for (int kk = 0; kk < 2; ++kk)
#pragma unroll
    for (int j = 0; j < 8; ++j)
      wf[kk][j] = (bf16_t)Wr[(kk * 32 + lg * 8 + j) * 16 + lc];  // Wr^T[h=lc][k]
  float brv[4];
#pragma unroll
  for (int j = 0; j < 4; ++j) brv[j] = br[lg * 4 + j];
  const float* relrow = rel + (size_t)pair * 512 * 64;
  const size_t mbase = (size_t)b * 512 * 512 + (size_t)qrow * 512;
  bf16_t* outb = biasM + (size_t)b * 16 * 512 * 512 + (size_t)qrow * 512;
  for (int kt = wid * 8; kt < wid * 8 + 8; ++kt) {
    const int k0 = kt * 16;
    const float* rrow = relrow + (size_t)(k0 + lc) * 64;
    f32x4 acc;
    acc[0] = brv[0]; acc[1] = brv[1]; acc[2] = brv[2]; acc[3] = brv[3];
#pragma unroll
    for (int kk = 0; kk < 2; ++kk) {
      const float4* s = (const float4*)(rrow + kk * 32 + lg * 8);
      float4 f0 = s[0], f1 = s[1];
      bf16x8 bfr;
      bfr[0] = (bf16_t)f0.x; bfr[1] = (bf16_t)f0.y; bfr[2] = (bf16_t)f0.z; bfr[3] = (bf16_t)f0.w;
      bfr[4] = (bf16_t)f1.x; bfr[5] = (bf16_t)f1.y; bfr[6] = (bf16_t)f1.z; bfr[7] = (bf16_t)f1.w;
      acc = mfma16(wf[kk], bfr, acc);
    }
    bool mb;
    if (isU8) mb = ((const unsigned char*)mask)[mbase + k0 + lc] != 0;
    else      mb = ((const int*)mask)[mbase + k0 + lc] != 0;
#pragma unroll
    for (int j = 0; j < 4; ++j) {
      const float valf = mb ? -1e9f : logf(fmaxf(acc[j], 1e-6f));
      outb[(size_t)(lg * 4 + j) * 512 * 512 + k0 + lc] = (bf16_t)valf;
    }
  }
}

// ---------------------------------------------------------------------------
// Flash attention. Block = (b, h, q-tile of 64); 4 waves x 16 q-rows each.
__global__ __launch_bounds__(256) void attn_kernel(
    const bf16_t* __restrict__ Qh, const bf16_t* __restrict__ Kh,
    const bf16_t* __restrict__ Vh, const bf16_t* __restrict__ biasM,
    bf16_t* __restrict__ atted) {
  __shared__ __align__(16) bf16_t Ksm[64 * 64];
  __shared__ __align__(16) bf16_t Vtsm[64 * 88];
  __shared__ __align__(16) bf16_t Psm[4 * 16 * 64];
  const int tid = threadIdx.x, wid = tid >> 6, lane = tid & 63;
  const int lg = lane >> 4, lc = lane & 15;
  const int bid = blockIdx.x;
  const int qt = bid & 7, h = (bid >> 3) & 15, b = bid >> 7;
  const size_t headoff = (size_t)(b * 16 + h) * 512 * 64;
  const bf16_t* Qb = Qh + headoff;
  const bf16_t* Kb = Kh + headoff;
  const bf16_t* Vb = Vh + headoff;
  const int q0 = qt * 64 + wid * 16;
  const bf16_t* biasb = biasM + ((size_t)(b * 16 + h) * 512 + q0) * 512;

  bf16x8 qf[2];
#pragma unroll
  for (int kk = 0; kk < 2; ++kk)
    qf[kk] = *(const bf16x8*)(Qb + (size_t)(q0 + lc) * 64 + kk * 32 + lg * 8);

  f32x4 Oacc[4];
#pragma unroll
  for (int ds = 0; ds < 4; ++ds) Oacc[ds] = zero4();
  float mrun[4], lrun[4];
#pragma unroll
  for (int j = 0; j < 4; ++j) { mrun[j] = -INFINITY; lrun[j] = 0.f; }

  const int krow = tid & 63, kc0 = (tid >> 6) * 2;
  const int vn = tid & 63, vd0 = (tid >> 6) * 16;
  bf16_t* Pw = Psm + wid * 16 * 64;

  for (int kt0 = 0; kt0 < 512; kt0 += 64) {
#pragma unroll
    for (int ci = 0; ci < 2; ++ci) {
      const int c = kc0 + ci;
      bf16x8 kv = *(const bf16x8*)(Kb + (size_t)(kt0 + krow) * 64 + c * 8);
      *(bf16x8*)(Ksm + krow * 64 + (c ^ (krow & 7)) * 8) = kv;
    }
    {
      bf16x8 v0 = *(const bf16x8*)(Vb + (size_t)(kt0 + vn) * 64 + vd0);
      bf16x8 v1 = *(const bf16x8*)(Vb + (size_t)(kt0 + vn) * 64 + vd0 + 8);
#pragma unroll
      for (int i = 0; i < 8; ++i) Vtsm[(vd0 + i) * 88 + vn] = v0[i];
#pragma unroll
      for (int i = 0; i < 8; ++i) Vtsm[(vd0 + 8 + i) * 88 + vn] = v1[i];
    }
    __syncthreads();

    f32x4 sacc[4];
#pragma unroll
    for (int quad = 0; quad < 4; ++quad) {
      sacc[quad] = zero4();
      const int kr = quad * 16 + lc;
#pragma unroll
      for (int kk = 0; kk < 2; ++kk) {
        bf16x8 kf = *(const bf16x8*)(Ksm + kr * 64 + ((kk * 4 + lg) ^ (kr & 7)) * 8);
        sacc[quad] = mfma16(qf[kk], kf, sacc[quad]);
      }
    }

    float p[4][4];
#pragma unroll
    for (int j = 0; j < 4; ++j) {
      float sv[4];
#pragma unroll
      for (int quad = 0; quad < 4; ++quad) {
        const float bias_v = (float)biasb[(size_t)(lg * 4 + j) * 512 + kt0 + quad * 16 + lc];
        sv[quad] = (bias_v < -1e8f) ? -1e9f : fmaf(sacc[quad][j], 0.125f, bias_v);
      }
      float tmax = fmaxf(fmaxf(sv[0], sv[1]), fmaxf(sv[2], sv[3]));
#pragma unroll
      for (int mm = 1; mm < 16; mm <<= 1) tmax = fmaxf(tmax, __shfl_xor(tmax, mm));
      const float mnew = fmaxf(mrun[j], tmax);
      const float sf = expf(mrun[j] - mnew);
      mrun[j] = mnew;
      lrun[j] *= sf;
#pragma unroll
      for (int ds = 0; ds < 4; ++ds) Oacc[ds][j] *= sf;
      float psum = 0.f;
#pragma unroll
      for (int quad = 0; quad < 4; ++quad) {
        const float pv = expf(sv[quad] - mnew);
        p[quad][j] = pv;
        psum += pv;
      }
      lrun[j] += psum;
    }

#pragma unroll
    for (int quad = 0; quad < 4; ++quad)
#pragma unroll
      for (int j = 0; j < 4; ++j) {
        const int row = lg * 4 + j, col = quad * 16 + lc;
        Pw[row * 64 + ((col >> 3) ^ (row & 7)) * 8 + (col & 7)] = (bf16_t)p[quad][j];
      }

#pragma unroll
    for (int kk = 0; kk < 2; ++kk) {
      bf16x8 pf = *(const bf16x8*)(Pw + lc * 64 + ((kk * 4 + lg) ^ (lc & 7)) * 8);
#pragma unroll
      for (int ds = 0; ds < 4; ++ds) {
        bf16x8 vf = *(const bf16x8*)(Vtsm + (ds * 16 + lc) * 88 + kk * 32 + lg * 8);
        Oacc[ds] = mfma16(pf, vf, Oacc[ds]);
      }
    }
    __syncthreads();
  }

#pragma unroll
  for (int j = 0; j < 4; ++j) {
    float l = lrun[j];
#pragma unroll
    for (int mm = 1; mm < 16; mm <<= 1) l += __shfl_xor(l, mm);
    lrun[j] = 1.0f / l;
  }
#pragma unroll
  for (int ds = 0; ds < 4; ++ds)
#pragma unroll
    for (int j = 0; j < 4; ++j) {
      const int n = q0 + lg * 4 + j;
      const int d = ds * 16 + lc;
      atted[((size_t)b * 512 + n) * 1024 + h * 64 + d] = (bf16_t)(Oacc[ds][j] * lrun[j]);
    }
}

// ---------------------------------------------------------------------------
// Output GEMM: d_out(f32) = atted(bf16 [2048][1024]) x Wmt(bf16 [1024][1024])^T
__global__ __launch_bounds__(256) void out_gemm(
    const bf16_t* __restrict__ A, const bf16_t* __restrict__ Bt, float* __restrict__ Out) {
  __shared__ __align__(16) bf16_t Asm[128 * 64];
  __shared__ __align__(16) bf16_t Bsm[128 * 64];
  const int tid = threadIdx.x, wid = tid >> 6, lane = tid & 63;
  const int lg = lane >> 4, lc = lane & 15;
  const int m0 = blockIdx.y * 128, n0 = blockIdx.x * 128;
  const int wm = (wid >> 1) * 64, wn = (wid & 1) * 64;
  const int srow = tid >> 1, sc0 = (tid & 1) * 4;
  const bf16_t* Arow = A + (size_t)(m0 + srow) * 1024;
  const bf16_t* Brow = Bt + (size_t)(n0 + srow) * 1024;
  f32x4 acc[4][4];
#pragma unroll
  for (int i = 0; i < 4; ++i)
#pragma unroll
    for (int j = 0; j < 4; ++j) acc[i][j] = zero4();

  for (int k0 = 0; k0 < 1024; k0 += 64) {
#pragma unroll
    for (int ci = 0; ci < 4; ++ci) {
      const int c = sc0 + ci;
      const int phys = c ^ (srow & 7);
      *(bf16x8*)(Asm + srow * 64 + phys * 8) = *(const bf16x8*)(Arow + k0 + c * 8);
      *(bf16x8*)(Bsm + srow * 64 + phys * 8) = *(const bf16x8*)(Brow + k0 + c * 8);
    }
    __syncthreads();
#pragma unroll
    for (int kk = 0; kk < 2; ++kk) {
      bf16x8 af[4], bfv[4];
#pragma unroll
      for (int i = 0; i < 4; ++i) {
        const int ar = wm + i * 16 + lc;
        af[i] = *(const bf16x8*)(Asm + ar * 64 + ((kk * 4 + lg) ^ (ar & 7)) * 8);
        const int brr = wn + i * 16 + lc;
        bfv[i] = *(const bf16x8*)(Bsm + brr * 64 + ((kk * 4 + lg) ^ (brr & 7)) * 8);
      }
#pragma unroll
      for (int mi = 0; mi < 4; ++mi)
#pragma unroll
        for (int ni = 0; ni < 4; ++ni) acc[mi][ni] = mfma16(af[mi], bfv[ni], acc[mi][ni]);
    }
    __syncthreads();
  }
#pragma unroll
  for (int mi = 0; mi < 4; ++mi)
#pragma unroll
    for (int ni = 0; ni < 4; ++ni)
#pragma unroll
      for (int j = 0; j < 4; ++j) {
        const int m = m0 + wm + mi * 16 + lg * 4 + j;
        const int col = n0 + wn + ni * 16 + lc;
        Out[(size_t)m * 1024 + col] = acc[mi][ni][j];
      }
}

// ---------------------------------------------------------------------------
extern "C" void kernel_launch(void* const* d_in, const int* in_sizes, int n_in,
                              void* d_out, int out_size, void* d_ws, size_t ws_size,
                              hipStream_t stream) {
  const float* v = (const float*)d_in[0];
  const float* k = (const float*)d_in[1];
  const float* q = (const float*)d_in[2];
  const void* mask = d_in[3];  // dtype (u8 vs i32) resolved on-device
  const float* rel = (const float*)d_in[4];
  const float* Wv = (const float*)d_in[5];
  const float* Wk = (const float*)d_in[6];
  const float* Wq = (const float*)d_in[7];
  const float* Wr = (const float*)d_in[8];
  const float* br = (const float*)d_in[9];
  const float* Wm = (const float*)d_in[10];

  char* ws = (char*)d_ws;
  // layout (bytes): [0,8M) Wt x4 (v,k,q,m); [8M) Qh; [12M) Kh; [16M) Vh;
  // [20M) biasM (33.6M); [54M) atted (4M); [58M) mask flag. total ~58 MB.
  bf16_t* Wt = (bf16_t*)ws;
  bf16_t* Qh = (bf16_t*)(ws + ((size_t)8 << 20));
  bf16_t* Kh = (bf16_t*)(ws + ((size_t)12 << 20));
  bf16_t* Vh = (bf16_t*)(ws + ((size_t)16 << 20));
  bf16_t* biasM = (bf16_t*)(ws + ((size_t)20 << 20));
  bf16_t* atted = (bf16_t*)(ws + ((size_t)54 << 20));
  int* mflag = (int*)(ws + ((size_t)58 << 20));
  bf16_t* Wvt = Wt + 0 * 1048576;
  bf16_t* Wkt = Wt + 1 * 1048576;
  bf16_t* Wqt = Wt + 2 * 1048576;
  bf16_t* Wmt = Wt + 3 * 1048576;

  detect_mask<<<dim3(1), 256, 0, stream>>>((const unsigned int*)mask, mflag);
  wtrans_kernel<<<dim3(16, 16, 4), 256, 0, stream>>>(Wv, Wk, Wq, Wm, Wt);
  proj_gemm<<<dim3(8, 16, 3), 256, 0, stream>>>(q, k, v, Wqt, Wkt, Wvt, Qh, Kh, Vh);
  bias_kernel<<<dim3(2048), 256, 0, stream>>>(rel, Wr, br, mask, mflag, biasM);
  attn_kernel<<<dim3(512), 256, 0, stream>>>(Qh, Kh, Vh, biasM, atted);
  out_gemm<<<dim3(8, 16), 256, 0, stream>>>(atted, Wmt, (float*)d_out);
}

// Round 3
// 183.615 us; speedup vs baseline: 1.0449x; 1.0449x over previous
//
#include <hip/hip_runtime.h>
#include <hip/hip_bf16.h>

// RelMHAtt: B=4, N=512, H=16, D=64, HS=1024, RS=64, SCALE=0.125
// Pipeline: wtrans(+mask probe) -> proj_gemm(q,k,v; Q pre-scaled) -> bias_kernel
//           -> attn_kernel (bias as QK acc-init, dbuf LDS) -> out_gemm

typedef __bf16 bf16_t;
typedef __bf16 bf16x8 __attribute__((ext_vector_type(8)));
typedef float f32x4 __attribute__((ext_vector_type(4)));

__device__ __forceinline__ f32x4 mfma16(bf16x8 a, bf16x8 b, f32x4 c) {
  return __builtin_amdgcn_mfma_f32_16x16x32_bf16(a, b, c, 0, 0, 0);
}
__device__ __forceinline__ f32x4 zero4() {
  f32x4 z; z[0] = 0.f; z[1] = 0.f; z[2] = 0.f; z[3] = 0.f; return z;
}

// ---------------------------------------------------------------------------
// Weight transpose + cast: W[1024][1024] f32 (in,out) -> Wt[1024][1024] bf16 (out,in)
// Block (0,0,0) additionally probes the mask dtype: uint32 view of a u8/bool
// mask contains words > 1; an int32 mask is all 0/1 words. flag=1 -> u8 path.
__global__ __launch_bounds__(256) void wtrans_kernel(
    const float* __restrict__ W0, const float* __restrict__ W1,
    const float* __restrict__ W2, const float* __restrict__ W3,
    bf16_t* __restrict__ OutBase,
    const unsigned int* __restrict__ mw, int* __restrict__ flag) {
  const float* W = blockIdx.z == 0 ? W0 : blockIdx.z == 1 ? W1 : blockIdx.z == 2 ? W2 : W3;
  bf16_t* Ot = OutBase + (size_t)blockIdx.z * 1024 * 1024;
  __shared__ float tile[64][68];
  __shared__ int sflag;
  const int tid = threadIdx.x;
  const bool probe = (blockIdx.x == 0 && blockIdx.y == 0 && blockIdx.z == 0);
  if (probe && tid == 0) sflag = 0;
  const int i0 = blockIdx.y * 64, j0 = blockIdx.x * 64;
  const int ri = tid >> 2, rc = (tid & 3) * 16;
  const float* src = W + (size_t)(i0 + ri) * 1024 + j0 + rc;
#pragma unroll
  for (int qq = 0; qq < 4; ++qq) {
    float4 f = *(const float4*)(src + qq * 4);
    *(float4*)(&tile[ri][rc + qq * 4]) = f;
  }
  if (probe) {
    int any = 0;
    for (int i = tid; i < 4096; i += 256) any |= (mw[i] > 1u) ? 1 : 0;
    if (any) atomicOr(&sflag, 1);
  }
  __syncthreads();
  const int wj = tid >> 2, wc = (tid & 3) * 16;
  bf16x8 o0, o1;
#pragma unroll
  for (int s = 0; s < 8; ++s) o0[s] = (bf16_t)tile[wc + s][wj];
#pragma unroll
  for (int s = 0; s < 8; ++s) o1[s] = (bf16_t)tile[wc + 8 + s][wj];
  bf16_t* dst = Ot + (size_t)(j0 + wj) * 1024 + i0 + wc;
  *(bf16x8*)dst = o0;
  *(bf16x8*)(dst + 8) = o1;
  if (probe && tid == 0) *flag = sflag;
}

// ---------------------------------------------------------------------------
// Projection GEMM: C = A(f32 [2048][1024]) x Bt(bf16 [1024][1024])^T,
// written bf16 into [b][h][n][d]. Q output (z==0) pre-scaled by 0.125.
__global__ __launch_bounds__(256) void proj_gemm(
    const float* __restrict__ Aq, const float* __restrict__ Ak, const float* __restrict__ Av,
    const bf16_t* __restrict__ Bq, const bf16_t* __restrict__ Bk, const bf16_t* __restrict__ Bv,
    bf16_t* __restrict__ Oq, bf16_t* __restrict__ Ok, bf16_t* __restrict__ Ov) {
  const int z = blockIdx.z;
  const float* A = (z == 0) ? Aq : (z == 1) ? Ak : Av;
  const bf16_t* Bt = (z == 0) ? Bq : (z == 1) ? Bk : Bv;
  bf16_t* Out = (z == 0) ? Oq : (z == 1) ? Ok : Ov;
  const float scl = (z == 0) ? 0.125f : 1.0f;
  __shared__ __align__(16) bf16_t Asm[128 * 64];
  __shared__ __align__(16) bf16_t Bsm[128 * 64];
  const int tid = threadIdx.x, wid = tid >> 6, lane = tid & 63;
  const int lg = lane >> 4, lc = lane & 15;
  const int m0 = blockIdx.y * 128, n0 = blockIdx.x * 128;
  const int wm = (wid >> 1) * 64, wn = (wid & 1) * 64;
  const int srow = tid >> 1, sc0 = (tid & 1) * 4;
  const float* Arow = A + (size_t)(m0 + srow) * 1024;
  const bf16_t* Brow = Bt + (size_t)(n0 + srow) * 1024;
  f32x4 acc[4][4];
#pragma unroll
  for (int i = 0; i < 4; ++i)
#pragma unroll
    for (int j = 0; j < 4; ++j) acc[i][j] = zero4();

  for (int k0 = 0; k0 < 1024; k0 += 64) {
#pragma unroll
    for (int ci = 0; ci < 4; ++ci) {
      const int c = sc0 + ci;
      const int phys = c ^ (srow & 7);
      const float4* s = (const float4*)(Arow + k0 + c * 8);
      float4 f0 = s[0], f1 = s[1];
      bf16x8 av;
      av[0] = (bf16_t)f0.x; av[1] = (bf16_t)f0.y; av[2] = (bf16_t)f0.z; av[3] = (bf16_t)f0.w;
      av[4] = (bf16_t)f1.x; av[5] = (bf16_t)f1.y; av[6] = (bf16_t)f1.z; av[7] = (bf16_t)f1.w;
      *(bf16x8*)(Asm + srow * 64 + phys * 8) = av;
      *(bf16x8*)(Bsm + srow * 64 + phys * 8) = *(const bf16x8*)(Brow + k0 + c * 8);
    }
    __syncthreads();
#pragma unroll
    for (int kk = 0; kk < 2; ++kk) {
      bf16x8 af[4], bfv[4];
#pragma unroll
      for (int i = 0; i < 4; ++i) {
        const int ar = wm + i * 16 + lc;
        af[i] = *(const bf16x8*)(Asm + ar * 64 + ((kk * 4 + lg) ^ (ar & 7)) * 8);
        const int brr = wn + i * 16 + lc;
        bfv[i] = *(const bf16x8*)(Bsm + brr * 64 + ((kk * 4 + lg) ^ (brr & 7)) * 8);
      }
#pragma unroll
      for (int mi = 0; mi < 4; ++mi)
#pragma unroll
        for (int ni = 0; ni < 4; ++ni) acc[mi][ni] = mfma16(af[mi], bfv[ni], acc[mi][ni]);
    }
    __syncthreads();
  }
#pragma unroll
  for (int mi = 0; mi < 4; ++mi)
#pragma unroll
    for (int ni = 0; ni < 4; ++ni)
#pragma unroll
      for (int j = 0; j < 4; ++j) {
        const int m = m0 + wm + mi * 16 + lg * 4 + j;
        const int col = n0 + wn + ni * 16 + lc;
        const int b = m >> 9, n = m & 511;
        const int h = col >> 6, d = col & 63;
        Out[(((size_t)(b * 16 + h)) * 512 + n) * 64 + d] = (bf16_t)(acc[mi][ni][j] * scl);
      }
}

// ---------------------------------------------------------------------------
// Bias: r = relu(rel_embed @ Wr + br); bias = log(max(r,1e-6)); masked -> -1e9.
// Swapped-operand MFMA; output bf16 [B][H][N][N]. Mask dtype chosen via flag.
__global__ __launch_bounds__(256) void bias_kernel(
    const float* __restrict__ rel, const float* __restrict__ Wr,
    const float* __restrict__ br, const void* __restrict__ mask,
    const int* __restrict__ mflag, bf16_t* __restrict__ biasM) {
  const int tid = threadIdx.x, wid = tid >> 6, lane = tid & 63;
  const int lg = lane >> 4, lc = lane & 15;
  const int pair = blockIdx.x;  // b*512 + q
  const int b = pair >> 9, qrow = pair & 511;
  const int isU8 = *mflag;
  bf16x8 wf[2];
#pragma unroll
  for (int kk = 0; kk < 2; ++kk)
#pragma unroll
    for (int j = 0; j < 8; ++j)
      wf[kk][j] = (bf16_t)Wr[(kk * 32 + lg * 8 + j) * 16 + lc];  // Wr^T[h=lc][k]
  float brv[4];
#pragma unroll
  for (int j = 0; j < 4; ++j) brv[j] = br[lg * 4 + j];
  const float* relrow = rel + (size_t)pair * 512 * 64;
  const size_t mbase = (size_t)b * 512 * 512 + (size_t)qrow * 512;
  bf16_t* outb = biasM + (size_t)b * 16 * 512 * 512 + (size_t)qrow * 512;
#pragma unroll 4
  for (int kt = wid * 8; kt < wid * 8 + 8; ++kt) {
    const int k0 = kt * 16;
    const float* rrow = relrow + (size_t)(k0 + lc) * 64;
    f32x4 acc;
    acc[0] = brv[0]; acc[1] = brv[1]; acc[2] = brv[2]; acc[3] = brv[3];
#pragma unroll
    for (int kk = 0; kk < 2; ++kk) {
      const float4* s = (const float4*)(rrow + kk * 32 + lg * 8);
      float4 f0 = s[0], f1 = s[1];
      bf16x8 bfr;
      bfr[0] = (bf16_t)f0.x; bfr[1] = (bf16_t)f0.y; bfr[2] = (bf16_t)f0.z; bfr[3] = (bf16_t)f0.w;
      bfr[4] = (bf16_t)f1.x; bfr[5] = (bf16_t)f1.y; bfr[6] = (bf16_t)f1.z; bfr[7] = (bf16_t)f1.w;
      acc = mfma16(wf[kk], bfr, acc);
    }
    bool mb;
    if (isU8) mb = ((const unsigned char*)mask)[mbase + k0 + lc] != 0;
    else      mb = ((const int*)mask)[mbase + k0 + lc] != 0;
#pragma unroll
    for (int j = 0; j < 4; ++j) {
      const float valf = mb ? -1e9f : __logf(fmaxf(acc[j], 1e-6f));
      outb[(size_t)(lg * 4 + j) * 512 * 512 + k0 + lc] = (bf16_t)valf;
    }
  }
}

// ---------------------------------------------------------------------------
// Flash attention. Block = (b, h, q-tile of 64); 4 waves x 16 q-rows each.
// Q pre-scaled by 0.125 upstream; bias tile loaded as the QK accumulator init
// (masked bias = -1e9 sentinel -> exp underflows to 0; no branch needed).
// K/V double-buffered in LDS: one barrier per tile, staging overlaps MFMA.
__global__ __launch_bounds__(256) void attn_kernel(
    const bf16_t* __restrict__ Qh, const bf16_t* __restrict__ Kh,
    const bf16_t* __restrict__ Vh, const bf16_t* __restrict__ biasM,
    bf16_t* __restrict__ atted) {
  __shared__ __align__(16) bf16_t Ksm[2][64 * 64];
  __shared__ __align__(16) bf16_t Vtsm[2][64 * 88];
  __shared__ __align__(16) bf16_t Psm[4 * 16 * 64];
  const int tid = threadIdx.x, wid = tid >> 6, lane = tid & 63;
  const int lg = lane >> 4, lc = lane & 15;
  const int bid = blockIdx.x;
  const int qt = bid & 7, h = (bid >> 3) & 15, b = bid >> 7;
  const size_t headoff = (size_t)(b * 16 + h) * 512 * 64;
  const bf16_t* Qb = Qh + headoff;
  const bf16_t* Kb = Kh + headoff;
  const bf16_t* Vb = Vh + headoff;
  const int q0 = qt * 64 + wid * 16;
  const bf16_t* biasb = biasM + ((size_t)(b * 16 + h) * 512 + q0) * 512;

  bf16x8 qf[2];
#pragma unroll
  for (int kk = 0; kk < 2; ++kk)
    qf[kk] = *(const bf16x8*)(Qb + (size_t)(q0 + lc) * 64 + kk * 32 + lg * 8);

  f32x4 Oacc[4];
#pragma unroll
  for (int ds = 0; ds < 4; ++ds) Oacc[ds] = zero4();
  float mrun[4], lrun[4];
#pragma unroll
  for (int j = 0; j < 4; ++j) { mrun[j] = -INFINITY; lrun[j] = 0.f; }

  const int krow = tid & 63, kc0 = (tid >> 6) * 2;
  const int vn = tid & 63, vd0 = (tid >> 6) * 16;
  bf16_t* Pw = Psm + wid * 16 * 64;

#define STAGE(T, BUF)                                                          \
  do {                                                                         \
    const int kb_ = (T) * 64;                                                  \
    _Pragma("unroll") for (int ci = 0; ci < 2; ++ci) {                         \
      const int c_ = kc0 + ci;                                                 \
      bf16x8 kv_ = *(const bf16x8*)(Kb + (size_t)(kb_ + krow) * 64 + c_ * 8);  \
      *(bf16x8*)(Ksm[BUF] + krow * 64 + (c_ ^ (krow & 7)) * 8) = kv_;          \
    }                                                                          \
    bf16x8 v0_ = *(const bf16x8*)(Vb + (size_t)(kb_ + vn) * 64 + vd0);         \
    bf16x8 v1_ = *(const bf16x8*)(Vb + (size_t)(kb_ + vn) * 64 + vd0 + 8);     \
    _Pragma("unroll") for (int i = 0; i < 8; ++i)                              \
        Vtsm[BUF][(vd0 + i) * 88 + vn] = v0_[i];                               \
    _Pragma("unroll") for (int i = 0; i < 8; ++i)                              \
        Vtsm[BUF][(vd0 + 8 + i) * 88 + vn] = v1_[i];                           \
  } while (0)

  STAGE(0, 0);
  __syncthreads();

  for (int t = 0; t < 8; ++t) {
    const int cur = t & 1;
    if (t < 7) STAGE(t + 1, cur ^ 1);

    // bias tile -> accumulator init (includes -1e9 mask sentinel)
    f32x4 sacc[4];
#pragma unroll
    for (int quad = 0; quad < 4; ++quad)
#pragma unroll
      for (int j = 0; j < 4; ++j)
        sacc[quad][j] = (float)biasb[(size_t)(lg * 4 + j) * 512 + t * 64 + quad * 16 + lc];

    const bf16_t* Kc = Ksm[cur];
#pragma unroll
    for (int quad = 0; quad < 4; ++quad) {
      const int kr = quad * 16 + lc;
#pragma unroll
      for (int kk = 0; kk < 2; ++kk) {
        bf16x8 kf = *(const bf16x8*)(Kc + kr * 64 + ((kk * 4 + lg) ^ (kr & 7)) * 8);
        sacc[quad] = mfma16(qf[kk], kf, sacc[quad]);
      }
    }

    float p[4][4];
#pragma unroll
    for (int j = 0; j < 4; ++j) {
      float tmax = fmaxf(fmaxf(sacc[0][j], sacc[1][j]), fmaxf(sacc[2][j], sacc[3][j]));
#pragma unroll
      for (int mm = 1; mm < 16; mm <<= 1) tmax = fmaxf(tmax, __shfl_xor(tmax, mm));
      const float mnew = fmaxf(mrun[j], tmax);
      const float sf = __expf(mrun[j] - mnew);
      mrun[j] = mnew;
      lrun[j] *= sf;
#pragma unroll
      for (int ds = 0; ds < 4; ++ds) Oacc[ds][j] *= sf;
      float psum = 0.f;
#pragma unroll
      for (int quad = 0; quad < 4; ++quad) {
        const float pv = __expf(sacc[quad][j] - mnew);
        p[quad][j] = pv;
        psum += pv;
      }
      lrun[j] += psum;
    }

#pragma unroll
    for (int quad = 0; quad < 4; ++quad)
#pragma unroll
      for (int j = 0; j < 4; ++j) {
        const int row = lg * 4 + j, col = quad * 16 + lc;
        Pw[row * 64 + ((col >> 3) ^ (row & 7)) * 8 + (col & 7)] = (bf16_t)p[quad][j];
      }

    const bf16_t* Vc = Vtsm[cur];
#pragma unroll
    for (int kk = 0; kk < 2; ++kk) {
      bf16x8 pf = *(const bf16x8*)(Pw + lc * 64 + ((kk * 4 + lg) ^ (lc & 7)) * 8);
#pragma unroll
      for (int ds = 0; ds < 4; ++ds) {
        bf16x8 vf = *(const bf16x8*)(Vc + (ds * 16 + lc) * 88 + kk * 32 + lg * 8);
        Oacc[ds] = mfma16(pf, vf, Oacc[ds]);
      }
    }
    __syncthreads();
  }
#undef STAGE

#pragma unroll
  for (int j = 0; j < 4; ++j) {
    float l = lrun[j];
#pragma unroll
    for (int mm = 1; mm < 16; mm <<= 1) l += __shfl_xor(l, mm);
    lrun[j] = 1.0f / l;
  }
#pragma unroll
  for (int ds = 0; ds < 4; ++ds)
#pragma unroll
    for (int j = 0; j < 4; ++j) {
      const int n = q0 + lg * 4 + j;
      const int d = ds * 16 + lc;
      atted[((size_t)b * 512 + n) * 1024 + h * 64 + d] = (bf16_t)(Oacc[ds][j] * lrun[j]);
    }
}

// ---------------------------------------------------------------------------
// Output GEMM: d_out(f32) = atted(bf16 [2048][1024]) x Wmt(bf16 [1024][1024])^T
__global__ __launch_bounds__(256) void out_gemm(
    const bf16_t* __restrict__ A, const bf16_t* __restrict__ Bt, float* __restrict__ Out) {
  __shared__ __align__(16) bf16_t Asm[128 * 64];
  __shared__ __align__(16) bf16_t Bsm[128 * 64];
  const int tid = threadIdx.x, wid = tid >> 6, lane = tid & 63;
  const int lg = lane >> 4, lc = lane & 15;
  const int m0 = blockIdx.y * 128, n0 = blockIdx.x * 128;
  const int wm = (wid >> 1) * 64, wn = (wid & 1) * 64;
  const int srow = tid >> 1, sc0 = (tid & 1) * 4;
  const bf16_t* Arow = A + (size_t)(m0 + srow) * 1024;
  const bf16_t* Brow = Bt + (size_t)(n0 + srow) * 1024;
  f32x4 acc[4][4];
#pragma unroll
  for (int i = 0; i < 4; ++i)
#pragma unroll
    for (int j = 0; j < 4; ++j) acc[i][j] = zero4();

  for (int k0 = 0; k0 < 1024; k0 += 64) {
#pragma unroll
    for (int ci = 0; ci < 4; ++ci) {
      const int c = sc0 + ci;
      const int phys = c ^ (srow & 7);
      *(bf16x8*)(Asm + srow * 64 + phys * 8) = *(const bf16x8*)(Arow + k0 + c * 8);
      *(bf16x8*)(Bsm + srow * 64 + phys * 8) = *(const bf16x8*)(Brow + k0 + c * 8);
    }
    __syncthreads();
#pragma unroll
    for (int kk = 0; kk < 2; ++kk) {
      bf16x8 af[4], bfv[4];
#pragma unroll
      for (int i = 0; i < 4; ++i) {
        const int ar = wm + i * 16 + lc;
        af[i] = *(const bf16x8*)(Asm + ar * 64 + ((kk * 4 + lg) ^ (ar & 7)) * 8);
        const int brr = wn + i * 16 + lc;
        bfv[i] = *(const bf16x8*)(Bsm + brr * 64 + ((kk * 4 + lg) ^ (brr & 7)) * 8);
      }
#pragma unroll
      for (int mi = 0; mi < 4; ++mi)
#pragma unroll
        for (int ni = 0; ni < 4; ++ni) acc[mi][ni] = mfma16(af[mi], bfv[ni], acc[mi][ni]);
    }
    __syncthreads();
  }
#pragma unroll
  for (int mi = 0; mi < 4; ++mi)
#pragma unroll
    for (int ni = 0; ni < 4; ++ni)
#pragma unroll
      for (int j = 0; j < 4; ++j) {
        const int m = m0 + wm + mi * 16 + lg * 4 + j;
        const int col = n0 + wn + ni * 16 + lc;
        Out[(size_t)m * 1024 + col] = acc[mi][ni][j];
      }
}

// ---------------------------------------------------------------------------
extern "C" void kernel_launch(void* const* d_in, const int* in_sizes, int n_in,
                              void* d_out, int out_size, void* d_ws, size_t ws_size,
                              hipStream_t stream) {
  const float* v = (const float*)d_in[0];
  const float* k = (const float*)d_in[1];
  const float* q = (const float*)d_in[2];
  const void* mask = d_in[3];  // dtype (u8 vs i32) resolved on-device
  const float* rel = (const float*)d_in[4];
  const float* Wv = (const float*)d_in[5];
  const float* Wk = (const float*)d_in[6];
  const float* Wq = (const float*)d_in[7];
  const float* Wr = (const float*)d_in[8];
  const float* br = (const float*)d_in[9];
  const float* Wm = (const float*)d_in[10];

  char* ws = (char*)d_ws;
  // layout (bytes): [0,8M) Wt x4 (v,k,q,m); [8M) Qh; [12M) Kh; [16M) Vh;
  // [20M) biasM (33.6M); [54M) atted (4M); [58M) mask flag. total ~58 MB.
  bf16_t* Wt = (bf16_t*)ws;
  bf16_t* Qh = (bf16_t*)(ws + ((size_t)8 << 20));
  bf16_t* Kh = (bf16_t*)(ws + ((size_t)12 << 20));
  bf16_t* Vh = (bf16_t*)(ws + ((size_t)16 << 20));
  bf16_t* biasM = (bf16_t*)(ws + ((size_t)20 << 20));
  bf16_t* atted = (bf16_t*)(ws + ((size_t)54 << 20));
  int* mflag = (int*)(ws + ((size_t)58 << 20));
  bf16_t* Wvt = Wt + 0 * 1048576;
  bf16_t* Wkt = Wt + 1 * 1048576;
  bf16_t* Wqt = Wt + 2 * 1048576;
  bf16_t* Wmt = Wt + 3 * 1048576;

  wtrans_kernel<<<dim3(16, 16, 4), 256, 0, stream>>>(Wv, Wk, Wq, Wm, Wt,
                                                     (const unsigned int*)mask, mflag);
  proj_gemm<<<dim3(8, 16, 3), 256, 0, stream>>>(q, k, v, Wqt, Wkt, Wvt, Qh, Kh, Vh);
  bias_kernel<<<dim3(2048), 256, 0, stream>>>(rel, Wr, br, mask, mflag, biasM);
  attn_kernel<<<dim3(512), 256, 0, stream>>>(Qh, Kh, Vh, biasM, atted);
  out_gemm<<<dim3(8, 16), 256, 0, stream>>>(atted, Wmt, (float*)d_out);
}

// Round 4
// 160.603 us; speedup vs baseline: 1.1947x; 1.1433x over previous
//
#include <hip/hip_runtime.h>
#include <hip/hip_bf16.h>

// RelMHAtt: B=4, N=512, H=16, D=64, HS=1024, RS=64, SCALE=0.125
// Pipeline: wtrans(+mask probe) -> cast_qkv -> proj_gemm2 (gload_lds) ->
//           bias_kernel -> attn_kernel -> out_gemm2 (gload_lds)

typedef __bf16 bf16_t;
typedef __bf16 bf16x8 __attribute__((ext_vector_type(8)));
typedef float f32x4 __attribute__((ext_vector_type(4)));

__device__ __forceinline__ f32x4 mfma16(bf16x8 a, bf16x8 b, f32x4 c) {
  return __builtin_amdgcn_mfma_f32_16x16x32_bf16(a, b, c, 0, 0, 0);
}
__device__ __forceinline__ f32x4 zero4() {
  f32x4 z; z[0] = 0.f; z[1] = 0.f; z[2] = 0.f; z[3] = 0.f; return z;
}

// async global->LDS, 16B per lane; LDS dest = wave-uniform base + lane*16B
#define GLOAD_LDS16(gptr, lptr)                                                   \
  __builtin_amdgcn_global_load_lds(                                               \
      (const __attribute__((address_space(1))) unsigned int*)(gptr),              \
      (__attribute__((address_space(3))) unsigned int*)(lptr), 16, 0, 0)

// ---------------------------------------------------------------------------
// Weight transpose + cast: W[1024][1024] f32 (in,out) -> Wt[1024][1024] bf16 (out,in)
// Block (0,0,0) probes mask dtype (u8 vs i32) -> flag.
__global__ __launch_bounds__(256) void wtrans_kernel(
    const float* __restrict__ W0, const float* __restrict__ W1,
    const float* __restrict__ W2, const float* __restrict__ W3,
    bf16_t* __restrict__ OutBase,
    const unsigned int* __restrict__ mw, int* __restrict__ flag) {
  const float* W = blockIdx.z == 0 ? W0 : blockIdx.z == 1 ? W1 : blockIdx.z == 2 ? W2 : W3;
  bf16_t* Ot = OutBase + (size_t)blockIdx.z * 1024 * 1024;
  __shared__ float tile[64][68];
  __shared__ int sflag;
  const int tid = threadIdx.x;
  const bool probe = (blockIdx.x == 0 && blockIdx.y == 0 && blockIdx.z == 0);
  if (probe && tid == 0) sflag = 0;
  const int i0 = blockIdx.y * 64, j0 = blockIdx.x * 64;
  const int ri = tid >> 2, rc = (tid & 3) * 16;
  const float* src = W + (size_t)(i0 + ri) * 1024 + j0 + rc;
#pragma unroll
  for (int qq = 0; qq < 4; ++qq) {
    float4 f = *(const float4*)(src + qq * 4);
    *(float4*)(&tile[ri][rc + qq * 4]) = f;
  }
  if (probe) {
    int any = 0;
    for (int i = tid; i < 4096; i += 256) any |= (mw[i] > 1u) ? 1 : 0;
    if (any) atomicOr(&sflag, 1);
  }
  __syncthreads();
  const int wj = tid >> 2, wc = (tid & 3) * 16;
  bf16x8 o0, o1;
#pragma unroll
  for (int s = 0; s < 8; ++s) o0[s] = (bf16_t)tile[wc + s][wj];
#pragma unroll
  for (int s = 0; s < 8; ++s) o1[s] = (bf16_t)tile[wc + 8 + s][wj];
  bf16_t* dst = Ot + (size_t)(j0 + wj) * 1024 + i0 + wc;
  *(bf16x8*)dst = o0;
  *(bf16x8*)(dst + 8) = o1;
  if (probe && tid == 0) *flag = sflag;
}

// ---------------------------------------------------------------------------
// Cast q/k/v f32 -> bf16 (q pre-scaled by 0.125; exact exponent shift).
__global__ __launch_bounds__(256) void cast_qkv(
    const float* __restrict__ q, const float* __restrict__ k, const float* __restrict__ v,
    bf16_t* __restrict__ Qc, bf16_t* __restrict__ Kc, bf16_t* __restrict__ Vc) {
  const size_t gid = (size_t)blockIdx.x * 256 + threadIdx.x;  // 786432 threads
  const int which = (int)(gid >> 18);
  const size_t off = (gid & 262143) * 8;
  const float* src = which == 0 ? q : which == 1 ? k : v;
  bf16_t* dst = which == 0 ? Qc : which == 1 ? Kc : Vc;
  const float scl = which == 0 ? 0.125f : 1.0f;
  float4 f0 = *(const float4*)(src + off);
  float4 f1 = *(const float4*)(src + off + 4);
  bf16x8 o;
  o[0] = (bf16_t)(f0.x * scl); o[1] = (bf16_t)(f0.y * scl);
  o[2] = (bf16_t)(f0.z * scl); o[3] = (bf16_t)(f0.w * scl);
  o[4] = (bf16_t)(f1.x * scl); o[5] = (bf16_t)(f1.y * scl);
  o[6] = (bf16_t)(f1.z * scl); o[7] = (bf16_t)(f1.w * scl);
  *(bf16x8*)(dst + off) = o;
}

// ---------------------------------------------------------------------------
// Projection GEMM v2 (m97 structure): C = A(bf16 [2048][1024]) x Bt(bf16)^T,
// global_load_lds(16B) staging, linear LDS dest + inverse-swizzled global src,
// XOR-swizzled reads. Output scattered bf16 into [b][h][n][d].
__global__ __launch_bounds__(256) void proj_gemm2(
    const bf16_t* __restrict__ Aq, const bf16_t* __restrict__ Ak, const bf16_t* __restrict__ Av,
    const bf16_t* __restrict__ Bq, const bf16_t* __restrict__ Bk, const bf16_t* __restrict__ Bv,
    bf16_t* __restrict__ Oq, bf16_t* __restrict__ Ok, bf16_t* __restrict__ Ov) {
  const int z = blockIdx.z;
  const bf16_t* A = (z == 0) ? Aq : (z == 1) ? Ak : Av;
  const bf16_t* Bt = (z == 0) ? Bq : (z == 1) ? Bk : Bv;
  bf16_t* Out = (z == 0) ? Oq : (z == 1) ? Ok : Ov;
  __shared__ __align__(16) bf16_t Asm[128 * 64];
  __shared__ __align__(16) bf16_t Bsm[128 * 64];
  const int tid = threadIdx.x, wid = tid >> 6, lane = tid & 63;
  const int lg = lane >> 4, lc = lane & 15;
  const int m0 = blockIdx.y * 128, n0 = blockIdx.x * 128;
  const int wm = (wid >> 1) * 64, wn = (wid & 1) * 64;
  // staging: per wave 4 gload_lds for A (32 rows) + 4 for B. lane -> (sr, phys chunk)
  const int sr = lane >> 3;          // row within 8-row group (== r&7)
  const int scch = lane & 7;         // phys chunk
  const int srcch = scch ^ sr;       // logical chunk fetched into phys slot
  const bf16_t* Ap[4];
  const bf16_t* Bp[4];
#pragma unroll
  for (int i = 0; i < 4; ++i) {
    const int r = wid * 32 + i * 8 + sr;
    Ap[i] = A + (size_t)(m0 + r) * 1024 + srcch * 8;
    Bp[i] = Bt + (size_t)(n0 + r) * 1024 + srcch * 8;
  }
  f32x4 acc[4][4];
#pragma unroll
  for (int i = 0; i < 4; ++i)
#pragma unroll
    for (int j = 0; j < 4; ++j) acc[i][j] = zero4();

  for (int k0 = 0; k0 < 1024; k0 += 64) {
#pragma unroll
    for (int i = 0; i < 4; ++i) {
      GLOAD_LDS16(Ap[i] + k0, Asm + (wid * 32 + i * 8) * 64);
      GLOAD_LDS16(Bp[i] + k0, Bsm + (wid * 32 + i * 8) * 64);
    }
    __syncthreads();
#pragma unroll
    for (int kk = 0; kk < 2; ++kk) {
      bf16x8 af[4], bfv[4];
#pragma unroll
      for (int i = 0; i < 4; ++i) {
        const int ar = wm + i * 16 + lc;
        af[i] = *(const bf16x8*)(Asm + ar * 64 + ((kk * 4 + lg) ^ (ar & 7)) * 8);
        const int brr = wn + i * 16 + lc;
        bfv[i] = *(const bf16x8*)(Bsm + brr * 64 + ((kk * 4 + lg) ^ (brr & 7)) * 8);
      }
#pragma unroll
      for (int mi = 0; mi < 4; ++mi)
#pragma unroll
        for (int ni = 0; ni < 4; ++ni) acc[mi][ni] = mfma16(af[mi], bfv[ni], acc[mi][ni]);
    }
    __syncthreads();
  }
#pragma unroll
  for (int mi = 0; mi < 4; ++mi)
#pragma unroll
    for (int ni = 0; ni < 4; ++ni)
#pragma unroll
      for (int j = 0; j < 4; ++j) {
        const int m = m0 + wm + mi * 16 + lg * 4 + j;
        const int col = n0 + wn + ni * 16 + lc;
        const int b = m >> 9, n = m & 511;
        const int h = col >> 6, d = col & 63;
        Out[(((size_t)(b * 16 + h)) * 512 + n) * 64 + d] = (bf16_t)acc[mi][ni][j];
      }
}

// ---------------------------------------------------------------------------
// Bias: r = relu(rel_embed @ Wr + br); bias = log(max(r,1e-6)); masked -> -1e9.
__global__ __launch_bounds__(256) void bias_kernel(
    const float* __restrict__ rel, const float* __restrict__ Wr,
    const float* __restrict__ br, const void* __restrict__ mask,
    const int* __restrict__ mflag, bf16_t* __restrict__ biasM) {
  const int tid = threadIdx.x, wid = tid >> 6, lane = tid & 63;
  const int lg = lane >> 4, lc = lane & 15;
  const int pair = blockIdx.x;  // b*512 + q
  const int b = pair >> 9, qrow = pair & 511;
  const int isU8 = *mflag;
  bf16x8 wf[2];
#pragma unroll
  for (int kk = 0; kk < 2; ++kk)
#pragma unroll
    for (int j = 0; j < 8; ++j)
      wf[kk][j] = (bf16_t)Wr[(kk * 32 + lg * 8 + j) * 16 + lc];  // Wr^T[h=lc][k]
  float brv[4];
#pragma unroll
  for (int j = 0; j < 4; ++j) brv[j] = br[lg * 4 + j];
  const float* relrow = rel + (size_t)pair * 512 * 64;
  const size_t mbase = (size_t)b * 512 * 512 + (size_t)qrow * 512;
  bf16_t* outb = biasM + (size_t)b * 16 * 512 * 512 + (size_t)qrow * 512;
#pragma unroll 4
  for (int kt = wid * 8; kt < wid * 8 + 8; ++kt) {
    const int k0 = kt * 16;
    const float* rrow = relrow + (size_t)(k0 + lc) * 64;
    f32x4 acc;
    acc[0] = brv[0]; acc[1] = brv[1]; acc[2] = brv[2]; acc[3] = brv[3];
#pragma unroll
    for (int kk = 0; kk < 2; ++kk) {
      const float4* s = (const float4*)(rrow + kk * 32 + lg * 8);
      float4 f0 = s[0], f1 = s[1];
      bf16x8 bfr;
      bfr[0] = (bf16_t)f0.x; bfr[1] = (bf16_t)f0.y; bfr[2] = (bf16_t)f0.z; bfr[3] = (bf16_t)f0.w;
      bfr[4] = (bf16_t)f1.x; bfr[5] = (bf16_t)f1.y; bfr[6] = (bf16_t)f1.z; bfr[7] = (bf16_t)f1.w;
      acc = mfma16(wf[kk], bfr, acc);
    }
    bool mb;
    if (isU8) mb = ((const unsigned char*)mask)[mbase + k0 + lc] != 0;
    else      mb = ((const int*)mask)[mbase + k0 + lc] != 0;
#pragma unroll
    for (int j = 0; j < 4; ++j) {
      const float valf = mb ? -1e9f : __logf(fmaxf(acc[j], 1e-6f));
      outb[(size_t)(lg * 4 + j) * 512 * 512 + k0 + lc] = (bf16_t)valf;
    }
  }
}

// ---------------------------------------------------------------------------
// Flash attention. Block = (b, h, q-tile of 64); 4 waves x 16 q-rows each.
// Bias tile is the QK accumulator init (masked = -1e9 sentinel).
__global__ __launch_bounds__(256) void attn_kernel(
    const bf16_t* __restrict__ Qh, const bf16_t* __restrict__ Kh,
    const bf16_t* __restrict__ Vh, const bf16_t* __restrict__ biasM,
    bf16_t* __restrict__ atted) {
  __shared__ __align__(16) bf16_t Ksm[2][64 * 64];
  __shared__ __align__(16) bf16_t Vtsm[2][64 * 88];
  __shared__ __align__(16) bf16_t Psm[4 * 16 * 64];
  const int tid = threadIdx.x, wid = tid >> 6, lane = tid & 63;
  const int lg = lane >> 4, lc = lane & 15;
  const int bid = blockIdx.x;
  const int qt = bid & 7, h = (bid >> 3) & 15, b = bid >> 7;
  const size_t headoff = (size_t)(b * 16 + h) * 512 * 64;
  const bf16_t* Qb = Qh + headoff;
  const bf16_t* Kb = Kh + headoff;
  const bf16_t* Vb = Vh + headoff;
  const int q0 = qt * 64 + wid * 16;
  const bf16_t* biasb = biasM + ((size_t)(b * 16 + h) * 512 + q0) * 512;

  bf16x8 qf[2];
#pragma unroll
  for (int kk = 0; kk < 2; ++kk)
    qf[kk] = *(const bf16x8*)(Qb + (size_t)(q0 + lc) * 64 + kk * 32 + lg * 8);

  f32x4 Oacc[4];
#pragma unroll
  for (int ds = 0; ds < 4; ++ds) Oacc[ds] = zero4();
  float mrun[4], lrun[4];
#pragma unroll
  for (int j = 0; j < 4; ++j) { mrun[j] = -INFINITY; lrun[j] = 0.f; }

  const int krow = tid & 63, kc0 = (tid >> 6) * 2;
  const int vn = tid & 63, vd0 = (tid >> 6) * 16;
  bf16_t* Pw = Psm + wid * 16 * 64;

#define STAGE(T, BUF)                                                          \
  do {                                                                         \
    const int kb_ = (T) * 64;                                                  \
    _Pragma("unroll") for (int ci = 0; ci < 2; ++ci) {                         \
      const int c_ = kc0 + ci;                                                 \
      bf16x8 kv_ = *(const bf16x8*)(Kb + (size_t)(kb_ + krow) * 64 + c_ * 8);  \
      *(bf16x8*)(Ksm[BUF] + krow * 64 + (c_ ^ (krow & 7)) * 8) = kv_;          \
    }                                                                          \
    bf16x8 v0_ = *(const bf16x8*)(Vb + (size_t)(kb_ + vn) * 64 + vd0);         \
    bf16x8 v1_ = *(const bf16x8*)(Vb + (size_t)(kb_ + vn) * 64 + vd0 + 8);     \
    _Pragma("unroll") for (int i = 0; i < 8; ++i)                              \
        Vtsm[BUF][(vd0 + i) * 88 + vn] = v0_[i];                               \
    _Pragma("unroll") for (int i = 0; i < 8; ++i)                              \
        Vtsm[BUF][(vd0 + 8 + i) * 88 + vn] = v1_[i];                           \
  } while (0)

  STAGE(0, 0);
  __syncthreads();

  for (int t = 0; t < 8; ++t) {
    const int cur = t & 1;
    if (t < 7) STAGE(t + 1, cur ^ 1);

    f32x4 sacc[4];
#pragma unroll
    for (int quad = 0; quad < 4; ++quad)
#pragma unroll
      for (int j = 0; j < 4; ++j)
        sacc[quad][j] = (float)biasb[(size_t)(lg * 4 + j) * 512 + t * 64 + quad * 16 + lc];

    const bf16_t* Kc = Ksm[cur];
#pragma unroll
    for (int quad = 0; quad < 4; ++quad) {
      const int kr = quad * 16 + lc;
#pragma unroll
      for (int kk = 0; kk < 2; ++kk) {
        bf16x8 kf = *(const bf16x8*)(Kc + kr * 64 + ((kk * 4 + lg) ^ (kr & 7)) * 8);
        sacc[quad] = mfma16(qf[kk], kf, sacc[quad]);
      }
    }

    float p[4][4];
#pragma unroll
    for (int j = 0; j < 4; ++j) {
      float tmax = fmaxf(fmaxf(sacc[0][j], sacc[1][j]), fmaxf(sacc[2][j], sacc[3][j]));
#pragma unroll
      for (int mm = 1; mm < 16; mm <<= 1) tmax = fmaxf(tmax, __shfl_xor(tmax, mm));
      const float mnew = fmaxf(mrun[j], tmax);
      const float sf = __expf(mrun[j] - mnew);
      mrun[j] = mnew;
      lrun[j] *= sf;
#pragma unroll
      for (int ds = 0; ds < 4; ++ds) Oacc[ds][j] *= sf;
      float psum = 0.f;
#pragma unroll
      for (int quad = 0; quad < 4; ++quad) {
        const float pv = __expf(sacc[quad][j] - mnew);
        p[quad][j] = pv;
        psum += pv;
      }
      lrun[j] += psum;
    }

#pragma unroll
    for (int quad = 0; quad < 4; ++quad)
#pragma unroll
      for (int j = 0; j < 4; ++j) {
        const int row = lg * 4 + j, col = quad * 16 + lc;
        Pw[row * 64 + ((col >> 3) ^ (row & 7)) * 8 + (col & 7)] = (bf16_t)p[quad][j];
      }

    const bf16_t* Vc = Vtsm[cur];
#pragma unroll
    for (int kk = 0; kk < 2; ++kk) {
      bf16x8 pf = *(const bf16x8*)(Pw + lc * 64 + ((kk * 4 + lg) ^ (lc & 7)) * 8);
#pragma unroll
      for (int ds = 0; ds < 4; ++ds) {
        bf16x8 vf = *(const bf16x8*)(Vc + (ds * 16 + lc) * 88 + kk * 32 + lg * 8);
        Oacc[ds] = mfma16(pf, vf, Oacc[ds]);
      }
    }
    __syncthreads();
  }
#undef STAGE

#pragma unroll
  for (int j = 0; j < 4; ++j) {
    float l = lrun[j];
#pragma unroll
    for (int mm = 1; mm < 16; mm <<= 1) l += __shfl_xor(l, mm);
    lrun[j] = 1.0f / l;
  }
#pragma unroll
  for (int ds = 0; ds < 4; ++ds)
#pragma unroll
    for (int j = 0; j < 4; ++j) {
      const int n = q0 + lg * 4 + j;
      const int d = ds * 16 + lc;
      atted[((size_t)b * 512 + n) * 1024 + h * 64 + d] = (bf16_t)(Oacc[ds][j] * lrun[j]);
    }
}

// ---------------------------------------------------------------------------
// Output GEMM v2 (m97 structure): d_out(f32) = atted(bf16) x Wmt(bf16)^T
__global__ __launch_bounds__(256) void out_gemm2(
    const bf16_t* __restrict__ A, const bf16_t* __restrict__ Bt, float* __restrict__ Out) {
  __shared__ __align__(16) bf16_t Asm[128 * 64];
  __shared__ __align__(16) bf16_t Bsm[128 * 64];
  const int tid = threadIdx.x, wid = tid >> 6, lane = tid & 63;
  const int lg = lane >> 4, lc = lane & 15;
  const int m0 = blockIdx.y * 128, n0 = blockIdx.x * 128;
  const int wm = (wid >> 1) * 64, wn = (wid & 1) * 64;
  const int sr = lane >> 3, scch = lane & 7;
  const int srcch = scch ^ sr;
  const bf16_t* Ap[4];
  const bf16_t* Bp[4];
#pragma unroll
  for (int i = 0; i < 4; ++i) {
    const int r = wid * 32 + i * 8 + sr;
    Ap[i] = A + (size_t)(m0 + r) * 1024 + srcch * 8;
    Bp[i] = Bt + (size_t)(n0 + r) * 1024 + srcch * 8;
  }
  f32x4 acc[4][4];
#pragma unroll
  for (int i = 0; i < 4; ++i)
#pragma unroll
    for (int j = 0; j < 4; ++j) acc[i][j] = zero4();

  for (int k0 = 0; k0 < 1024; k0 += 64) {
#pragma unroll
    for (int i = 0; i < 4; ++i) {
      GLOAD_LDS16(Ap[i] + k0, Asm + (wid * 32 + i * 8) * 64);
      GLOAD_LDS16(Bp[i] + k0, Bsm + (wid * 32 + i * 8) * 64);
    }
    __syncthreads();
#pragma unroll
    for (int kk = 0; kk < 2; ++kk) {
      bf16x8 af[4], bfv[4];
#pragma unroll
      for (int i = 0; i < 4; ++i) {
        const int ar = wm + i * 16 + lc;
        af[i] = *(const bf16x8*)(Asm + ar * 64 + ((kk * 4 + lg) ^ (ar & 7)) * 8);
        const int brr = wn + i * 16 + lc;
        bfv[i] = *(const bf16x8*)(Bsm + brr * 64 + ((kk * 4 + lg) ^ (brr & 7)) * 8);
      }
#pragma unroll
      for (int mi = 0; mi < 4; ++mi)
#pragma unroll
        for (int ni = 0; ni < 4; ++ni) acc[mi][ni] = mfma16(af[mi], bfv[ni], acc[mi][ni]);
    }
    __syncthreads();
  }
#pragma unroll
  for (int mi = 0; mi < 4; ++mi)
#pragma unroll
    for (int ni = 0; ni < 4; ++ni)
#pragma unroll
      for (int j = 0; j < 4; ++j) {
        const int m = m0 + wm + mi * 16 + lg * 4 + j;
        const int col = n0 + wn + ni * 16 + lc;
        Out[(size_t)m * 1024 + col] = acc[mi][ni][j];
      }
}

// ---------------------------------------------------------------------------
extern "C" void kernel_launch(void* const* d_in, const int* in_sizes, int n_in,
                              void* d_out, int out_size, void* d_ws, size_t ws_size,
                              hipStream_t stream) {
  const float* v = (const float*)d_in[0];
  const float* k = (const float*)d_in[1];
  const float* q = (const float*)d_in[2];
  const void* mask = d_in[3];  // dtype (u8 vs i32) resolved on-device
  const float* rel = (const float*)d_in[4];
  const float* Wv = (const float*)d_in[5];
  const float* Wk = (const float*)d_in[6];
  const float* Wq = (const float*)d_in[7];
  const float* Wr = (const float*)d_in[8];
  const float* br = (const float*)d_in[9];
  const float* Wm = (const float*)d_in[10];

  char* ws = (char*)d_ws;
  // layout (MiB): [0,8) Wt x4 (v,k,q,m); [8,12) Qh; [12,16) Kh; [16,20) Vh;
  // [20,52) biasM; [52,56) atted; [56,60) Qc; [60,64) Kc; [64,68) Vc; [68] mflag.
  bf16_t* Wt = (bf16_t*)ws;
  bf16_t* Qh = (bf16_t*)(ws + ((size_t)8 << 20));
  bf16_t* Kh = (bf16_t*)(ws + ((size_t)12 << 20));
  bf16_t* Vh = (bf16_t*)(ws + ((size_t)16 << 20));
  bf16_t* biasM = (bf16_t*)(ws + ((size_t)20 << 20));
  bf16_t* atted = (bf16_t*)(ws + ((size_t)52 << 20));
  bf16_t* Qc = (bf16_t*)(ws + ((size_t)56 << 20));
  bf16_t* Kc = (bf16_t*)(ws + ((size_t)60 << 20));
  bf16_t* Vc = (bf16_t*)(ws + ((size_t)64 << 20));
  int* mflag = (int*)(ws + ((size_t)68 << 20));
  bf16_t* Wvt = Wt + 0 * 1048576;
  bf16_t* Wkt = Wt + 1 * 1048576;
  bf16_t* Wqt = Wt + 2 * 1048576;
  bf16_t* Wmt = Wt + 3 * 1048576;

  wtrans_kernel<<<dim3(16, 16, 4), 256, 0, stream>>>(Wv, Wk, Wq, Wm, Wt,
                                                     (const unsigned int*)mask, mflag);
  cast_qkv<<<dim3(3072), 256, 0, stream>>>(q, k, v, Qc, Kc, Vc);
  proj_gemm2<<<dim3(8, 16, 3), 256, 0, stream>>>(Qc, Kc, Vc, Wqt, Wkt, Wvt, Qh, Kh, Vh);
  bias_kernel<<<dim3(2048), 256, 0, stream>>>(rel, Wr, br, mask, mflag, biasM);
  attn_kernel<<<dim3(512), 256, 0, stream>>>(Qh, Kh, Vh, biasM, atted);
  out_gemm2<<<dim3(8, 16), 256, 0, stream>>>(atted, Wmt, (float*)d_out);
}

// Round 5
// 144.773 us; speedup vs baseline: 1.3253x; 1.1093x over previous
//
#include <hip/hip_runtime.h>
#include <hip/hip_bf16.h>

// RelMHAtt: B=4, N=512, H=16, D=64, HS=1024, RS=64, SCALE=0.125
// Pipeline: prep(wtrans+cast+probe) -> fat(bias ∪ proj_gemm) -> attn -> out_gemm
// fat merges the two independent long poles (BW-bound bias, MFMA-bound proj)
// into one launch so the hardware co-schedules them.

typedef __bf16 bf16_t;
typedef __bf16 bf16x8 __attribute__((ext_vector_type(8)));
typedef float f32x4 __attribute__((ext_vector_type(4)));

__device__ __forceinline__ f32x4 mfma16(bf16x8 a, bf16x8 b, f32x4 c) {
  return __builtin_amdgcn_mfma_f32_16x16x32_bf16(a, b, c, 0, 0, 0);
}
__device__ __forceinline__ f32x4 zero4() {
  f32x4 z; z[0] = 0.f; z[1] = 0.f; z[2] = 0.f; z[3] = 0.f; return z;
}

// async global->LDS, 16B per lane; LDS dest = wave-uniform base + lane*16B
#define GLOAD_LDS16(gptr, lptr)                                                   \
  __builtin_amdgcn_global_load_lds(                                               \
      (const __attribute__((address_space(1))) unsigned int*)(gptr),              \
      (__attribute__((address_space(3))) unsigned int*)(lptr), 16, 0, 0)

// ---------------------------------------------------------------------------
// prep: blocks [0,1024) = weight transpose+cast (W f32 [in][out] -> bf16 [out][in]),
//       blocks [1024,4096) = q/k/v f32->bf16 cast (q pre-scaled 0.125).
// Block 0 also probes mask dtype (u32 view of u8 mask has words>1) -> mflag.
__global__ __launch_bounds__(256) void prep_kernel(
    const float* __restrict__ W0, const float* __restrict__ W1,
    const float* __restrict__ W2, const float* __restrict__ W3,
    bf16_t* __restrict__ OutBase,
    const float* __restrict__ q, const float* __restrict__ k, const float* __restrict__ v,
    bf16_t* __restrict__ Qc, bf16_t* __restrict__ Kc, bf16_t* __restrict__ Vc,
    const unsigned int* __restrict__ mw, int* __restrict__ flag) {
  const int tid = threadIdx.x;
  if (blockIdx.x >= 1024) {
    const size_t gid = (size_t)(blockIdx.x - 1024) * 256 + tid;  // 786432 threads
    const int which = (int)(gid >> 18);
    const size_t off = (gid & 262143) * 8;
    const float* src = which == 0 ? q : which == 1 ? k : v;
    bf16_t* dst = which == 0 ? Qc : which == 1 ? Kc : Vc;
    const float scl = which == 0 ? 0.125f : 1.0f;
    float4 f0 = *(const float4*)(src + off);
    float4 f1 = *(const float4*)(src + off + 4);
    bf16x8 o;
    o[0] = (bf16_t)(f0.x * scl); o[1] = (bf16_t)(f0.y * scl);
    o[2] = (bf16_t)(f0.z * scl); o[3] = (bf16_t)(f0.w * scl);
    o[4] = (bf16_t)(f1.x * scl); o[5] = (bf16_t)(f1.y * scl);
    o[6] = (bf16_t)(f1.z * scl); o[7] = (bf16_t)(f1.w * scl);
    *(bf16x8*)(dst + off) = o;
    return;
  }
  const int wz = blockIdx.x >> 8, wy = (blockIdx.x >> 4) & 15, wx = blockIdx.x & 15;
  const float* W = wz == 0 ? W0 : wz == 1 ? W1 : wz == 2 ? W2 : W3;
  bf16_t* Ot = OutBase + (size_t)wz * 1024 * 1024;
  __shared__ float tile[64][68];
  __shared__ int sflag;
  const bool probe = (blockIdx.x == 0);
  if (probe && tid == 0) sflag = 0;
  const int i0 = wy * 64, j0 = wx * 64;
  const int ri = tid >> 2, rc = (tid & 3) * 16;
  const float* src = W + (size_t)(i0 + ri) * 1024 + j0 + rc;
#pragma unroll
  for (int qq = 0; qq < 4; ++qq) {
    float4 f = *(const float4*)(src + qq * 4);
    *(float4*)(&tile[ri][rc + qq * 4]) = f;
  }
  if (probe) {
    int any = 0;
    for (int i = tid; i < 4096; i += 256) any |= (mw[i] > 1u) ? 1 : 0;
    if (any) atomicOr(&sflag, 1);
  }
  __syncthreads();
  const int wj = tid >> 2, wc = (tid & 3) * 16;
  bf16x8 o0, o1;
#pragma unroll
  for (int s = 0; s < 8; ++s) o0[s] = (bf16_t)tile[wc + s][wj];
#pragma unroll
  for (int s = 0; s < 8; ++s) o1[s] = (bf16_t)tile[wc + 8 + s][wj];
  bf16_t* dst = Ot + (size_t)(j0 + wj) * 1024 + i0 + wc;
  *(bf16x8*)dst = o0;
  *(bf16x8*)(dst + 8) = o1;
  if (probe && tid == 0) *flag = sflag;
}

// ---------------------------------------------------------------------------
// fat: blocks [0,2048) = bias (BW-bound), blocks [2048,2432) = proj GEMM
// (MFMA-bound). Block-uniform branch; co-resident blocks overlap HBM & MFMA.
__global__ __launch_bounds__(256) void fat_kernel(
    // bias
    const float* __restrict__ rel, const float* __restrict__ Wr,
    const float* __restrict__ br, const void* __restrict__ mask,
    const int* __restrict__ mflag, bf16_t* __restrict__ biasM,
    // proj
    const bf16_t* __restrict__ Aq, const bf16_t* __restrict__ Ak, const bf16_t* __restrict__ Av,
    const bf16_t* __restrict__ Bq, const bf16_t* __restrict__ Bk, const bf16_t* __restrict__ Bv,
    bf16_t* __restrict__ Oq, bf16_t* __restrict__ Ok, bf16_t* __restrict__ Ov) {
  __shared__ __align__(16) bf16_t Asm[128 * 64];
  __shared__ __align__(16) bf16_t Bsm[128 * 64];
  const int tid = threadIdx.x, wid = tid >> 6, lane = tid & 63;
  const int lg = lane >> 4, lc = lane & 15;

  if (blockIdx.x < 2048) {
    // ---- bias path: r = relu(rel@Wr+br); bias=log(max(r,1e-6)); masked -> -1e9
    const int pair = blockIdx.x;  // b*512 + q
    const int b = pair >> 9, qrow = pair & 511;
    const int isU8 = *mflag;
    bf16x8 wf[2];
#pragma unroll
    for (int kk = 0; kk < 2; ++kk)
#pragma unroll
      for (int j = 0; j < 8; ++j)
        wf[kk][j] = (bf16_t)Wr[(kk * 32 + lg * 8 + j) * 16 + lc];  // Wr^T[h=lc][k]
    float brv[4];
#pragma unroll
    for (int j = 0; j < 4; ++j) brv[j] = br[lg * 4 + j];
    const float* relrow = rel + (size_t)pair * 512 * 64;
    const size_t mbase = (size_t)b * 512 * 512 + (size_t)qrow * 512;
    bf16_t* outb = biasM + (size_t)b * 16 * 512 * 512 + (size_t)qrow * 512;
#pragma unroll 4
    for (int kt = wid * 8; kt < wid * 8 + 8; ++kt) {
      const int k0 = kt * 16;
      const float* rrow = relrow + (size_t)(k0 + lc) * 64;
      f32x4 acc;
      acc[0] = brv[0]; acc[1] = brv[1]; acc[2] = brv[2]; acc[3] = brv[3];
#pragma unroll
      for (int kk = 0; kk < 2; ++kk) {
        const float4* s = (const float4*)(rrow + kk * 32 + lg * 8);
        float4 f0 = s[0], f1 = s[1];
        bf16x8 bfr;
        bfr[0] = (bf16_t)f0.x; bfr[1] = (bf16_t)f0.y; bfr[2] = (bf16_t)f0.z; bfr[3] = (bf16_t)f0.w;
        bfr[4] = (bf16_t)f1.x; bfr[5] = (bf16_t)f1.y; bfr[6] = (bf16_t)f1.z; bfr[7] = (bf16_t)f1.w;
        acc = mfma16(wf[kk], bfr, acc);
      }
      bool mb;
      if (isU8) mb = ((const unsigned char*)mask)[mbase + k0 + lc] != 0;
      else      mb = ((const int*)mask)[mbase + k0 + lc] != 0;
#pragma unroll
      for (int j = 0; j < 4; ++j) {
        const float valf = mb ? -1e9f : __logf(fmaxf(acc[j], 1e-6f));
        outb[(size_t)(lg * 4 + j) * 512 * 512 + k0 + lc] = (bf16_t)valf;
      }
    }
    return;
  }

  // ---- proj path: C = A(bf16 [2048][1024]) x Bt(bf16)^T -> [b][h][n][d] bf16
  const int idx = blockIdx.x - 2048;             // 384 blocks: (z, by, bx)
  const int z = idx >> 7, rem = idx & 127;
  const int byy = rem >> 3, bxx = rem & 7;
  const bf16_t* A = (z == 0) ? Aq : (z == 1) ? Ak : Av;
  const bf16_t* Bt = (z == 0) ? Bq : (z == 1) ? Bk : Bv;
  bf16_t* Out = (z == 0) ? Oq : (z == 1) ? Ok : Ov;
  const int m0 = byy * 128, n0 = bxx * 128;
  const int wm = (wid >> 1) * 64, wn = (wid & 1) * 64;
  const int sr = lane >> 3;          // row within 8-row group (== r&7)
  const int scch = lane & 7;         // phys chunk
  const int srcch = scch ^ sr;       // logical chunk fetched into phys slot
  const bf16_t* Ap[4];
  const bf16_t* Bp[4];
#pragma unroll
  for (int i = 0; i < 4; ++i) {
    const int r = wid * 32 + i * 8 + sr;
    Ap[i] = A + (size_t)(m0 + r) * 1024 + srcch * 8;
    Bp[i] = Bt + (size_t)(n0 + r) * 1024 + srcch * 8;
  }
  f32x4 acc[4][4];
#pragma unroll
  for (int i = 0; i < 4; ++i)
#pragma unroll
    for (int j = 0; j < 4; ++j) acc[i][j] = zero4();

  for (int k0 = 0; k0 < 1024; k0 += 64) {
#pragma unroll
    for (int i = 0; i < 4; ++i) {
      GLOAD_LDS16(Ap[i] + k0, Asm + (wid * 32 + i * 8) * 64);
      GLOAD_LDS16(Bp[i] + k0, Bsm + (wid * 32 + i * 8) * 64);
    }
    __syncthreads();
#pragma unroll
    for (int kk = 0; kk < 2; ++kk) {
      bf16x8 af[4], bfv[4];
#pragma unroll
      for (int i = 0; i < 4; ++i) {
        const int ar = wm + i * 16 + lc;
        af[i] = *(const bf16x8*)(Asm + ar * 64 + ((kk * 4 + lg) ^ (ar & 7)) * 8);
        const int brr = wn + i * 16 + lc;
        bfv[i] = *(const bf16x8*)(Bsm + brr * 64 + ((kk * 4 + lg) ^ (brr & 7)) * 8);
      }
#pragma unroll
      for (int mi = 0; mi < 4; ++mi)
#pragma unroll
        for (int ni = 0; ni < 4; ++ni) acc[mi][ni] = mfma16(af[mi], bfv[ni], acc[mi][ni]);
    }
    __syncthreads();
  }
#pragma unroll
  for (int mi = 0; mi < 4; ++mi)
#pragma unroll
    for (int ni = 0; ni < 4; ++ni)
#pragma unroll
      for (int j = 0; j < 4; ++j) {
        const int m = m0 + wm + mi * 16 + lg * 4 + j;
        const int col = n0 + wn + ni * 16 + lc;
        const int b = m >> 9, n = m & 511;
        const int h = col >> 6, d = col & 63;
        Out[(((size_t)(b * 16 + h)) * 512 + n) * 64 + d] = (bf16_t)acc[mi][ni][j];
      }
}

// ---------------------------------------------------------------------------
// Flash attention. Block = (b, h, q-tile of 64); 4 waves x 16 q-rows each.
// Bias tile is the QK accumulator init (masked = -1e9 sentinel).
__global__ __launch_bounds__(256) void attn_kernel(
    const bf16_t* __restrict__ Qh, const bf16_t* __restrict__ Kh,
    const bf16_t* __restrict__ Vh, const bf16_t* __restrict__ biasM,
    bf16_t* __restrict__ atted) {
  __shared__ __align__(16) bf16_t Ksm[2][64 * 64];
  __shared__ __align__(16) bf16_t Vtsm[2][64 * 88];
  __shared__ __align__(16) bf16_t Psm[4 * 16 * 64];
  const int tid = threadIdx.x, wid = tid >> 6, lane = tid & 63;
  const int lg = lane >> 4, lc = lane & 15;
  const int bid = blockIdx.x;
  const int qt = bid & 7, h = (bid >> 3) & 15, b = bid >> 7;
  const size_t headoff = (size_t)(b * 16 + h) * 512 * 64;
  const bf16_t* Qb = Qh + headoff;
  const bf16_t* Kb = Kh + headoff;
  const bf16_t* Vb = Vh + headoff;
  const int q0 = qt * 64 + wid * 16;
  const bf16_t* biasb = biasM + ((size_t)(b * 16 + h) * 512 + q0) * 512;

  bf16x8 qf[2];
#pragma unroll
  for (int kk = 0; kk < 2; ++kk)
    qf[kk] = *(const bf16x8*)(Qb + (size_t)(q0 + lc) * 64 + kk * 32 + lg * 8);

  f32x4 Oacc[4];
#pragma unroll
  for (int ds = 0; ds < 4; ++ds) Oacc[ds] = zero4();
  float mrun[4], lrun[4];
#pragma unroll
  for (int j = 0; j < 4; ++j) { mrun[j] = -INFINITY; lrun[j] = 0.f; }

  const int krow = tid & 63, kc0 = (tid >> 6) * 2;
  const int vn = tid & 63, vd0 = (tid >> 6) * 16;
  bf16_t* Pw = Psm + wid * 16 * 64;

#define STAGE(T, BUF)                                                          \
  do {                                                                         \
    const int kb_ = (T) * 64;                                                  \
    _Pragma("unroll") for (int ci = 0; ci < 2; ++ci) {                         \
      const int c_ = kc0 + ci;                                                 \
      bf16x8 kv_ = *(const bf16x8*)(Kb + (size_t)(kb_ + krow) * 64 + c_ * 8);  \
      *(bf16x8*)(Ksm[BUF] + krow * 64 + (c_ ^ (krow & 7)) * 8) = kv_;          \
    }                                                                          \
    bf16x8 v0_ = *(const bf16x8*)(Vb + (size_t)(kb_ + vn) * 64 + vd0);         \
    bf16x8 v1_ = *(const bf16x8*)(Vb + (size_t)(kb_ + vn) * 64 + vd0 + 8);     \
    _Pragma("unroll") for (int i = 0; i < 8; ++i)                              \
        Vtsm[BUF][(vd0 + i) * 88 + vn] = v0_[i];                               \
    _Pragma("unroll") for (int i = 0; i < 8; ++i)                              \
        Vtsm[BUF][(vd0 + 8 + i) * 88 + vn] = v1_[i];                           \
  } while (0)

  STAGE(0, 0);
  __syncthreads();

  for (int t = 0; t < 8; ++t) {
    const int cur = t & 1;
    if (t < 7) STAGE(t + 1, cur ^ 1);

    f32x4 sacc[4];
#pragma unroll
    for (int quad = 0; quad < 4; ++quad)
#pragma unroll
      for (int j = 0; j < 4; ++j)
        sacc[quad][j] = (float)biasb[(size_t)(lg * 4 + j) * 512 + t * 64 + quad * 16 + lc];

    const bf16_t* Kc = Ksm[cur];
#pragma unroll
    for (int quad = 0; quad < 4; ++quad) {
      const int kr = quad * 16 + lc;
#pragma unroll
      for (int kk = 0; kk < 2; ++kk) {
        bf16x8 kf = *(const bf16x8*)(Kc + kr * 64 + ((kk * 4 + lg) ^ (kr & 7)) * 8);
        sacc[quad] = mfma16(qf[kk], kf, sacc[quad]);
      }
    }

    float p[4][4];
#pragma unroll
    for (int j = 0; j < 4; ++j) {
      float tmax = fmaxf(fmaxf(sacc[0][j], sacc[1][j]), fmaxf(sacc[2][j], sacc[3][j]));
#pragma unroll
      for (int mm = 1; mm < 16; mm <<= 1) tmax = fmaxf(tmax, __shfl_xor(tmax, mm));
      const float mnew = fmaxf(mrun[j], tmax);
      const float sf = __expf(mrun[j] - mnew);
      mrun[j] = mnew;
      lrun[j] *= sf;
#pragma unroll
      for (int ds = 0; ds < 4; ++ds) Oacc[ds][j] *= sf;
      float psum = 0.f;
#pragma unroll
      for (int quad = 0; quad < 4; ++quad) {
        const float pv = __expf(sacc[quad][j] - mnew);
        p[quad][j] = pv;
        psum += pv;
      }
      lrun[j] += psum;
    }

#pragma unroll
    for (int quad = 0; quad < 4; ++quad)
#pragma unroll
      for (int j = 0; j < 4; ++j) {
        const int row = lg * 4 + j, col = quad * 16 + lc;
        Pw[row * 64 + ((col >> 3) ^ (row & 7)) * 8 + (col & 7)] = (bf16_t)p[quad][j];
      }

    const bf16_t* Vc = Vtsm[cur];
#pragma unroll
    for (int kk = 0; kk < 2; ++kk) {
      bf16x8 pf = *(const bf16x8*)(Pw + lc * 64 + ((kk * 4 + lg) ^ (lc & 7)) * 8);
#pragma unroll
      for (int ds = 0; ds < 4; ++ds) {
        bf16x8 vf = *(const bf16x8*)(Vc + (ds * 16 + lc) * 88 + kk * 32 + lg * 8);
        Oacc[ds] = mfma16(pf, vf, Oacc[ds]);
      }
    }
    __syncthreads();
  }
#undef STAGE

#pragma unroll
  for (int j = 0; j < 4; ++j) {
    float l = lrun[j];
#pragma unroll
    for (int mm = 1; mm < 16; mm <<= 1) l += __shfl_xor(l, mm);
    lrun[j] = 1.0f / l;
  }
#pragma unroll
  for (int ds = 0; ds < 4; ++ds)
#pragma unroll
    for (int j = 0; j < 4; ++j) {
      const int n = q0 + lg * 4 + j;
      const int d = ds * 16 + lc;
      atted[((size_t)b * 512 + n) * 1024 + h * 64 + d] = (bf16_t)(Oacc[ds][j] * lrun[j]);
    }
}

// ---------------------------------------------------------------------------
// Output GEMM (m97 structure): d_out(f32) = atted(bf16) x Wmt(bf16)^T
__global__ __launch_bounds__(256) void out_gemm2(
    const bf16_t* __restrict__ A, const bf16_t* __restrict__ Bt, float* __restrict__ Out) {
  __shared__ __align__(16) bf16_t Asm[128 * 64];
  __shared__ __align__(16) bf16_t Bsm[128 * 64];
  const int tid = threadIdx.x, wid = tid >> 6, lane = tid & 63;
  const int lg = lane >> 4, lc = lane & 15;
  const int m0 = blockIdx.y * 128, n0 = blockIdx.x * 128;
  const int wm = (wid >> 1) * 64, wn = (wid & 1) * 64;
  const int sr = lane >> 3, scch = lane & 7;
  const int srcch = scch ^ sr;
  const bf16_t* Ap[4];
  const bf16_t* Bp[4];
#pragma unroll
  for (int i = 0; i < 4; ++i) {
    const int r = wid * 32 + i * 8 + sr;
    Ap[i] = A + (size_t)(m0 + r) * 1024 + srcch * 8;
    Bp[i] = Bt + (size_t)(n0 + r) * 1024 + srcch * 8;
  }
  f32x4 acc[4][4];
#pragma unroll
  for (int i = 0; i < 4; ++i)
#pragma unroll
    for (int j = 0; j < 4; ++j) acc[i][j] = zero4();

  for (int k0 = 0; k0 < 1024; k0 += 64) {
#pragma unroll
    for (int i = 0; i < 4; ++i) {
      GLOAD_LDS16(Ap[i] + k0, Asm + (wid * 32 + i * 8) * 64);
      GLOAD_LDS16(Bp[i] + k0, Bsm + (wid * 32 + i * 8) * 64);
    }
    __syncthreads();
#pragma unroll
    for (int kk = 0; kk < 2; ++kk) {
      bf16x8 af[4], bfv[4];
#pragma unroll
      for (int i = 0; i < 4; ++i) {
        const int ar = wm + i * 16 + lc;
        af[i] = *(const bf16x8*)(Asm + ar * 64 + ((kk * 4 + lg) ^ (ar & 7)) * 8);
        const int brr = wn + i * 16 + lc;
        bfv[i] = *(const bf16x8*)(Bsm + brr * 64 + ((kk * 4 + lg) ^ (brr & 7)) * 8);
      }
#pragma unroll
      for (int mi = 0; mi < 4; ++mi)
#pragma unroll
        for (int ni = 0; ni < 4; ++ni) acc[mi][ni] = mfma16(af[mi], bfv[ni], acc[mi][ni]);
    }
    __syncthreads();
  }
#pragma unroll
  for (int mi = 0; mi < 4; ++mi)
#pragma unroll
    for (int ni = 0; ni < 4; ++ni)
#pragma unroll
      for (int j = 0; j < 4; ++j) {
        const int m = m0 + wm + mi * 16 + lg * 4 + j;
        const int col = n0 + wn + ni * 16 + lc;
        Out[(size_t)m * 1024 + col] = acc[mi][ni][j];
      }
}

// ---------------------------------------------------------------------------
extern "C" void kernel_launch(void* const* d_in, const int* in_sizes, int n_in,
                              void* d_out, int out_size, void* d_ws, size_t ws_size,
                              hipStream_t stream) {
  const float* v = (const float*)d_in[0];
  const float* k = (const float*)d_in[1];
  const float* q = (const float*)d_in[2];
  const void* mask = d_in[3];  // dtype (u8 vs i32) resolved on-device
  const float* rel = (const float*)d_in[4];
  const float* Wv = (const float*)d_in[5];
  const float* Wk = (const float*)d_in[6];
  const float* Wq = (const float*)d_in[7];
  const float* Wr = (const float*)d_in[8];
  const float* br = (const float*)d_in[9];
  const float* Wm = (const float*)d_in[10];

  char* ws = (char*)d_ws;
  // layout (MiB): [0,8) Wt x4 (v,k,q,m); [8,12) Qh; [12,16) Kh; [16,20) Vh;
  // [20,52) biasM; [52,56) atted; [56,60) Qc; [60,64) Kc; [64,68) Vc; [68] mflag.
  bf16_t* Wt = (bf16_t*)ws;
  bf16_t* Qh = (bf16_t*)(ws + ((size_t)8 << 20));
  bf16_t* Kh = (bf16_t*)(ws + ((size_t)12 << 20));
  bf16_t* Vh = (bf16_t*)(ws + ((size_t)16 << 20));
  bf16_t* biasM = (bf16_t*)(ws + ((size_t)20 << 20));
  bf16_t* atted = (bf16_t*)(ws + ((size_t)52 << 20));
  bf16_t* Qc = (bf16_t*)(ws + ((size_t)56 << 20));
  bf16_t* Kc = (bf16_t*)(ws + ((size_t)60 << 20));
  bf16_t* Vc = (bf16_t*)(ws + ((size_t)64 << 20));
  int* mflag = (int*)(ws + ((size_t)68 << 20));
  bf16_t* Wvt = Wt + 0 * 1048576;
  bf16_t* Wkt = Wt + 1 * 1048576;
  bf16_t* Wqt = Wt + 2 * 1048576;
  bf16_t* Wmt = Wt + 3 * 1048576;

  prep_kernel<<<dim3(4096), 256, 0, stream>>>(Wv, Wk, Wq, Wm, Wt, q, k, v, Qc, Kc, Vc,
                                              (const unsigned int*)mask, mflag);
  fat_kernel<<<dim3(2432), 256, 0, stream>>>(rel, Wr, br, mask, mflag, biasM,
                                             Qc, Kc, Vc, Wqt, Wkt, Wvt, Qh, Kh, Vh);
  attn_kernel<<<dim3(512), 256, 0, stream>>>(Qh, Kh, Vh, biasM, atted);
  out_gemm2<<<dim3(8, 16), 256, 0, stream>>>(atted, Wmt, (float*)d_out);
}